// Round 1
// baseline (228.935 us; speedup 1.0000x reference)
//
#include <hip/hip_runtime.h>
#include <hip/hip_bf16.h>
#include <cstdint>
#include <cstddef>

#define NN 10000
#define NE 160000

typedef unsigned short u16;
typedef __attribute__((ext_vector_type(8))) short short8;
typedef __attribute__((ext_vector_type(4))) float f32x4;

__device__ __forceinline__ float b2f(u16 u){
    union { uint32_t i; float f; } v; v.i = ((uint32_t)u) << 16; return v.f;
}
__device__ __forceinline__ u16 f2b(float f){
    union { __hip_bfloat16 h; u16 u; } c; c.h = __float2bfloat16(f); return c.u;
}
__device__ __forceinline__ float silu_f(float x){ return x / (1.f + __expf(-x)); }
__device__ __forceinline__ float ldr(const void* p, int i, int bf){
    return bf ? b2f(((const u16*)p)[i]) : ((const float*)p)[i];
}

// ---------------- workspace layout (4-byte word offsets) ----------------
constexpr size_t W_FLAG = 0;                        // 16 (flag[0] = anomaly count)
constexpr size_t W_CNT  = 16;                       // 10000
constexpr size_t W_OFFS = 10016;                    // 10001
constexpr size_t W_CUR  = 20032;                    // 10000
constexpr size_t W_SSND = 30032;                    // 160000 (sender per sorted pos)
constexpr size_t W_ATT  = 350032;                   // 100000
constexpr size_t W_POS  = 450032;                   // 30000
constexpr size_t W_SHF  = 480032;                   // 480000
constexpr size_t W_WGT  = 960032;
constexpr size_t OW_EMB = 0;
constexpr size_t OW_UP0 = 640;
constexpr size_t OW_R10 = 4736;
constexpr size_t OW_R20 = 5248;
constexpr size_t OW_R30 = 9344;
constexpr size_t OW_MIX0= 25728;
constexpr size_t OW_SC0 = 42112;
constexpr size_t OW_PR0 = 83072;
constexpr size_t OW_UP1 = 83264;
constexpr size_t OW_R11 = 87360;
constexpr size_t OW_R21 = 87872;
constexpr size_t OW_R31 = 91968;
constexpr size_t OW_MIX1= 108352;
constexpr size_t OW_SC1 = 124736;
constexpr size_t OW_PR1 = 165696;
constexpr size_t OW_RD0 = 165888;
constexpr size_t OW_ML1 = 165952;
constexpr size_t OW_ML2 = 166976;
constexpr size_t OW_TEND = 167000;
constexpr size_t W_BES  = W_WGT + OW_TEND;          // [E][8] f32 (fallback tier only)
constexpr size_t W_NF0  = W_BES + (size_t)NE*8;     // [N,64]
constexpr size_t W_H    = W_NF0 + (size_t)NN*64;
constexpr size_t W_A    = W_H   + (size_t)NN*64;    // h1 buffer in fused path; A in fallback
constexpr size_t W_NF1  = W_A   + (size_t)NN*64;
constexpr size_t W_R0   = W_NF1 + (size_t)NN*64;    // [E][64] bf16, RECEIVER-SORTED
constexpr size_t W_R1   = W_R0  + (size_t)NE*32;
constexpr size_t WP_DUAL   = W_R1 + (size_t)NE*32;  // packed weights 2 x 10400 u16
constexpr size_t WP_SINGLE = W_R0 + (size_t)NE*32;
constexpr size_t W_RS_D = WP_DUAL   + 10400;        // sorted distances [E] f32
constexpr size_t W_RS_S = WP_SINGLE + 10400;
constexpr size_t W_RS_F = W_R0;                     // fallback: rs at R0 slot (no R in fallback)
constexpr size_t WP_F   = W_R0 + NE;                // fallback: dummy wpack target

constexpr size_t NEED_DUAL   = (W_RS_D + NE) * 4;   // ~61.5 MB (ws measured ~268 MB)
constexpr size_t NEED_SINGLE = (W_RS_S + NE) * 4;   // ~41.0 MB

constexpr int OCT  = 520;   // weight per-oct stride (u16)
constexpr int OCTS = 136;   // activation per-oct stride (u16), 16 rows

// ---------------- detect (dtype) + histogram, one grid ----------------
__global__ void k_dh(const uint32_t* __restrict__ attrs, const int* __restrict__ rcv,
                     int* __restrict__ flag, int* __restrict__ cnt){
    int i = blockIdx.x * 256 + threadIdx.x;          // 625*256 == NE
    int c = 0;
    if (i < 50000){
        uint32_t v = attrs[i];
        c = (v != 0u && v != 0x3F800000u) ? 1 : 0;
    }
    unsigned long long m = __ballot(c);
    if ((threadIdx.x & 63) == 0 && m)
        atomicAdd(flag, (int)__popcll(m));
    if (i < NE) atomicAdd(&cnt[rcv[i]], 1);
}

// ---------------- merged: scan (block 0) + convert (1..30) + wpack (31..32) + embed_h (33..657) ----------------
struct PrepArgs { const void* s[21]; float* d[21]; int n[21]; };
__global__ __launch_bounds__(1024) void k_scan_prep(PrepArgs a, const int* __restrict__ flag,
        const int* __restrict__ cnt, int* __restrict__ offs, int* __restrict__ cur,
        u16* __restrict__ WP, float* __restrict__ nf0, float* __restrict__ h){
    int bf = flag[0] > 100;
    int t = threadIdx.x;
    if (blockIdx.x == 0){
        __shared__ int cl[10000];
        __shared__ int part[1024];
        for (int i = t; i < 10000; i += 1024) cl[i] = cnt[i];
        __syncthreads();
        int base = t * 10;
        int s = 0;
        #pragma unroll
        for (int i = 0; i < 10; i++) if (base + i < NN) s += cl[base + i];
        part[t] = s; __syncthreads();
        for (int d = 1; d < 1024; d <<= 1){
            int v = part[t];
            if (t >= d) v += part[t - d];
            __syncthreads();
            part[t] = v;
            __syncthreads();
        }
        int run = part[t] - s;
        #pragma unroll
        for (int i = 0; i < 10; i++){
            int idx = base + i;
            if (idx < NN){ offs[idx] = run; cur[idx] = run; run += cl[idx]; }
        }
        if (t == 1023) offs[NN] = part[1023];
    } else if (blockIdx.x < 31){
        int stride = 30 * 1024;
        int t0 = (blockIdx.x - 1) * 1024 + t;
        for (int k = 0; k < 21; k++){
            float* d = a.d[k]; int n = a.n[k];
            if (bf){
                const u16* s = (const u16*)a.s[k];
                for (int i = t0; i < n; i += stride) d[i] = b2f(s[i]);
            } else {
                const float* s = (const float*)a.s[k];
                for (int i = t0; i < n; i += stride) d[i] = s[i];
            }
        }
    } else if (blockIdx.x < 33){
        int b = blockIdx.x - 31;
        const void* W1 = a.s[b ? 12 : 5];
        const void* W2 = a.s[b ? 13 : 6];
        const void* W3 = a.s[b ? 14 : 7];
        u16* dst = WP + b * 10400;
        for (int i = t; i < 5200; i += 1024) ((uint32_t*)dst)[i] = 0;
        __syncthreads();
        for (int i = t; i < 512; i += 1024){
            int n = i >> 3, k = i & 7;
            dst[n*8 + k] = f2b(ldr(W1, k*64 + n, bf));
        }
        for (int i = t; i < 2048; i += 1024){
            int k = (i >> 6) * 2, n = i & 63;
            uint32_t p2 = ((uint32_t)f2b(ldr(W2, (k+1)*64 + n, bf)) << 16) | f2b(ldr(W2, k*64 + n, bf));
            uint32_t p3 = ((uint32_t)f2b(ldr(W3, (k+1)*256 + 4*n, bf)) << 16) | f2b(ldr(W3, k*256 + 4*n, bf));
            *(uint32_t*)&dst[2080 + (k>>3)*OCT + n*8 + (k&7)] = p2;
            *(uint32_t*)&dst[6240 + (k>>3)*OCT + n*8 + (k&7)] = p3;
        }
    } else {
        int nb = blockIdx.x - 33;                  // [0, 625): 16 nodes per block
        int n = nb*16 + (t >> 6);
        int l = t & 63;
        const void* attrs = a.s[1];
        const void* Wemb  = a.s[3];
        const void* Wup0  = a.s[4];
        float acc = 0.f;
        #pragma unroll
        for (int s = 0; s < 10; s++) acc += ldr(attrs, n*10 + s, bf) * ldr(Wemb, s*64 + l, bf);
        nf0[n*64 + l] = acc;
        float hv = 0.f;
        #pragma unroll 16
        for (int g = 0; g < 64; g++) hv += __shfl(acc, g) * ldr(Wup0, g*64 + l, bf);
        h[n*64 + l] = hv;
    }
}

// ---------------- scatter edge -> sorted slot; fused distance (raw inputs) ----------------
__global__ void k_scatter_r(const int* __restrict__ rcv, const int* __restrict__ snd,
        const void* __restrict__ posr, const void* __restrict__ shfr,
        int* __restrict__ cur, int* __restrict__ ssnd, float* __restrict__ rs,
        const int* __restrict__ flag){
    int e = blockIdx.x * 256 + threadIdx.x;
    if (e >= NE) return;
    int bf = flag[0] > 100;
    int r = rcv[e], s = snd[e];
    float vx = ldr(posr, r*3+0, bf) - ldr(posr, s*3+0, bf) + ldr(shfr, e*3+0, bf);
    float vy = ldr(posr, r*3+1, bf) - ldr(posr, s*3+1, bf) + ldr(shfr, e*3+1, bf);
    float vz = ldr(posr, r*3+2, bf) - ldr(posr, s*3+2, bf) + ldr(shfr, e*3+2, bf);
    float rr = sqrtf(vx*vx + vy*vy + vz*vz);
    int p = atomicAdd(&cur[r], 1);
    ssnd[p] = s;
    rs[p] = rr;
}

// ---------------- bessel expansion (fallback tier only) ----------------
__global__ void k_bess(const float* __restrict__ rs, float* __restrict__ bessp){
    int p = blockIdx.x * 256 + threadIdx.x;
    if (p >= NE) return;
    float rr = rs[p];
    float xr = rr * 0.1f;
    float x2 = xr*xr; float x5 = x2*x2*xr;
    float env = 1.f - 21.f*x5 + 35.f*x5*xr - 15.f*x5*x2;
    if (xr >= 1.f) env = 0.f;
    float scl = 0.4472135954999579f * env / (rr + 1e-9f);
    float b[8];
    #pragma unroll
    for (int n = 1; n <= 8; n++)
        b[n-1] = scl * sinf((float)n * 3.14159265358979323846f * rr * 0.1f);
    float4* be = (float4*)(bessp + (size_t)p*8);
    be[0] = make_float4(b[0], b[1], b[2], b[3]);
    be[1] = make_float4(b[4], b[5], b[6], b[7]);
}

// ---------------- MFMA radial MLP: block = 256 edges; bessel computed inline from rs ----------------
// Grid must be 2*nblk0 (dual) or nblk0 >= gridDim.x (single); nblk0 = NE/256 = 625 per half.
__global__ __launch_bounds__(256) void k_mlp_mfma(const float* __restrict__ rs,
        const u16* __restrict__ WPa, const u16* __restrict__ WPb,
        u16* __restrict__ R0, u16* __restrict__ R1, int nblk0){
    __shared__ __align__(16) u16 W[10400];
    __shared__ __align__(16) u16 X[4][20*OCTS];
    int half = blockIdx.x >= nblk0;
    int blk  = half ? blockIdx.x - nblk0 : blockIdx.x;
    const u16* WP = half ? WPb : WPa;
    u16* R = half ? R1 : R0;
    int t = threadIdx.x;
    int w = t >> 6, lane = t & 63;
    int q = lane >> 4, r = lane & 15;
    u16* Xw = &X[w][0];
    // stage pre-packed weights: 10400 u16 = 1300 uint4
    for (int i = t; i < 1300; i += 256) ((uint4*)W)[i] = ((const uint4*)WP)[i];
    // zero Xc octs 1..3 (K-padding), per-wave region
    {
        uint32_t* xz = (uint32_t*)(Xw + OCTS);
        for (int i = lane; i < 204; i += 64) xz[i] = 0;
    }
    __syncthreads();
    int pbase = blk * 256 + w * 64;
    #pragma unroll 1
    for (int st = 0; st < 4; st++){
        int pb = pbase + st * 16;
        // bessel inline: lane covers (edge = lane>>2, k = 2*(lane&3), +1)
        {
            float rr = rs[pb + (lane >> 2)];
            float xr = rr * 0.1f;
            float x2 = xr*xr, x5 = x2*x2*xr;
            float env = 1.f - 21.f*x5 + 35.f*x5*xr - 15.f*x5*x2;
            if (xr >= 1.f) env = 0.f;
            float scl = 0.4472135954999579f * env / (rr + 1e-9f);
            int k0 = (lane & 3) * 2;
            float b0 = scl * __sinf((float)(k0+1) * 0.3141592653589793f * rr);
            float b1 = scl * __sinf((float)(k0+2) * 0.3141592653589793f * rr);
            ((uint32_t*)Xw)[lane] = ((uint32_t)f2b(b1) << 16) | f2b(b0);
        }
        // ---- layer 1: K=8 (padded to 32) ----
        {
            short8 a = *(const short8*)&Xw[q*OCTS + r*8];
            #pragma unroll
            for (int nt = 0; nt < 4; nt++){
                short8 b = *(const short8*)&W[q*OCT + (nt*16 + r)*8];
                f32x4 c = {0.f, 0.f, 0.f, 0.f};
                c = __builtin_amdgcn_mfma_f32_16x16x32_bf16(a, b, c, 0, 0, 0);
                #pragma unroll
                for (int g = 0; g < 4; g++){
                    int e = q*4 + g;
                    int n = nt*16 + r;
                    Xw[(4 + (n>>3))*OCTS + e*8 + (n&7)] = f2b(silu_f(c[g]));
                }
            }
        }
        // ---- layer 2: K=64 ----
        {
            short8 a0 = *(const short8*)&Xw[(4+q)*OCTS + r*8];
            short8 a1 = *(const short8*)&Xw[(8+q)*OCTS + r*8];
            #pragma unroll
            for (int nt = 0; nt < 4; nt++){
                short8 b0 = *(const short8*)&W[2080 + q*OCT + (nt*16 + r)*8];
                short8 b1 = *(const short8*)&W[2080 + (4+q)*OCT + (nt*16 + r)*8];
                f32x4 c = {0.f, 0.f, 0.f, 0.f};
                c = __builtin_amdgcn_mfma_f32_16x16x32_bf16(a0, b0, c, 0, 0, 0);
                c = __builtin_amdgcn_mfma_f32_16x16x32_bf16(a1, b1, c, 0, 0, 0);
                #pragma unroll
                for (int g = 0; g < 4; g++){
                    int e = q*4 + g;
                    int n = nt*16 + r;
                    Xw[(12 + (n>>3))*OCTS + e*8 + (n&7)] = f2b(silu_f(c[g]));
                }
            }
        }
        // ---- layer 3: K=64, store R (bf16, receiver-sorted) ----
        {
            short8 a0 = *(const short8*)&Xw[(12+q)*OCTS + r*8];
            short8 a1 = *(const short8*)&Xw[(16+q)*OCTS + r*8];
            #pragma unroll
            for (int nt = 0; nt < 4; nt++){
                short8 b0 = *(const short8*)&W[6240 + q*OCT + (nt*16 + r)*8];
                short8 b1 = *(const short8*)&W[6240 + (4+q)*OCT + (nt*16 + r)*8];
                f32x4 c = {0.f, 0.f, 0.f, 0.f};
                c = __builtin_amdgcn_mfma_f32_16x16x32_bf16(a0, b0, c, 0, 0, 0);
                c = __builtin_amdgcn_mfma_f32_16x16x32_bf16(a1, b1, c, 0, 0, 0);
                #pragma unroll
                for (int g = 0; g < 4; g++){
                    int e = q*4 + g;
                    int n = nt*16 + r;
                    R[(size_t)(pb + e)*64 + n] = f2b(c[g]);
                }
            }
        }
    }
}

// ---------------- fused gather + node update + readout ----------------
template<int LAST>
__global__ __launch_bounds__(256) void k_gnode(const int* __restrict__ offs,
        const int* __restrict__ ssnd, const float* __restrict__ h, const u16* __restrict__ R,
        const float* __restrict__ nf, const float* __restrict__ attrs,
        const float* __restrict__ Wmix0, const float* __restrict__ Wsc,
        const float* __restrict__ Wprod, const float* __restrict__ Wtail,
        const float* __restrict__ Wml2, const float* __restrict__ Wup1,
        float* __restrict__ nf1out, float* __restrict__ hout,
        void* __restrict__ out, const int* __restrict__ flag){
    int wv = threadIdx.x >> 6;
    int n  = blockIdx.x * 4 + wv;
    int l  = threadIdx.x & 63;
    int beg = __builtin_amdgcn_readfirstlane(offs[n]);
    int end = __builtin_amdgcn_readfirstlane(offs[n+1]);
    float acc = 0.f;
    int p = beg;
    for (; p + 4 <= end; p += 4){
        int s0 = __builtin_amdgcn_readfirstlane(ssnd[p+0]);
        int s1 = __builtin_amdgcn_readfirstlane(ssnd[p+1]);
        int s2 = __builtin_amdgcn_readfirstlane(ssnd[p+2]);
        int s3 = __builtin_amdgcn_readfirstlane(ssnd[p+3]);
        float r0 = b2f(R[(size_t)(p+0)*64 + l]);
        float r1 = b2f(R[(size_t)(p+1)*64 + l]);
        float r2 = b2f(R[(size_t)(p+2)*64 + l]);
        float r3 = b2f(R[(size_t)(p+3)*64 + l]);
        acc += h[s0*64 + l]*r0 + h[s1*64 + l]*r1 + h[s2*64 + l]*r2 + h[s3*64 + l]*r3;
    }
    for (; p < end; p++){
        int s = __builtin_amdgcn_readfirstlane(ssnd[p]);
        acc += h[s*64 + l] * b2f(R[(size_t)p*64 + l]);
    }
    float Af  = acc * 0.0625f;
    float nff = nf[n*64 + l];
    float am = 0.f;
    #pragma unroll 16
    for (int f = 0; f < 64; f++) am += __shfl(Af, f) * Wmix0[f*64 + l];
    float sc = 0.f;
    for (int s = 0; s < 10; s++){
        float av = attrs[n*10 + s];       // wave-uniform
        if (av != 0.f){
            const float* Ws = Wsc + s*4096;
            float t = 0.f;
            #pragma unroll 16
            for (int f = 0; f < 64; f++) t += __shfl(nff, f) * Ws[f*64 + l];
            sc += av * t;
        }
    }
    float poly = Wprod[l] + Wprod[64 + l]*am + Wprod[128 + l]*am*am;
    float val = am*poly + sc;
    float rv;
    if (LAST == 0){
        nf1out[n*64 + l] = val;
        float hv = 0.f;
        #pragma unroll 16
        for (int g = 0; g < 64; g++) hv += __shfl(val, g) * Wup1[g*64 + l];
        hout[n*64 + l] = hv;              // separate buffer: h is still being gathered by other blocks
        rv = val * Wtail[l];
    } else {
        int lj = l & 15;                  // all 64 lanes run the shfl loop (divergent shfl is UB)
        float t = 0.f;
        #pragma unroll 16
        for (int g = 0; g < 64; g++){
            float vg = __shfl(val, g);
            t += vg * Wtail[g*16 + lj];
        }
        rv = (l < 16) ? (silu_f(t) * Wml2[lj]) : 0.f;
    }
    #pragma unroll
    for (int o2 = 32; o2; o2 >>= 1) rv += __shfl_down(rv, o2);
    if (l == 0){
        int idx = 2*n + LAST;
        if (flag[0] > 100) ((__hip_bfloat16*)out)[idx] = __float2bfloat16(rv);
        else               ((float*)out)[idx] = rv;
    }
}

// ---------------- legacy fused msg + node (fallback tier only) ----------------
__global__ __launch_bounds__(256) void k_msg_fused(const int* __restrict__ offs,
        const int* __restrict__ ssnd, const float* __restrict__ h, const float* __restrict__ bessp,
        const float* __restrict__ W1, const float* __restrict__ W2, const float* __restrict__ W3,
        float* __restrict__ A){
    int wv = threadIdx.x >> 6;
    int n  = blockIdx.x * 4 + wv;
    int l  = threadIdx.x & 63;
    float w1c[8];
    #pragma unroll
    for (int i = 0; i < 8; i++) w1c[i] = W1[i*64 + l];
    float w2c[64];
    #pragma unroll
    for (int j = 0; j < 64; j++) w2c[j] = W2[j*64 + l];
    float w3c[64];
    #pragma unroll
    for (int j = 0; j < 64; j++) w3c[j] = W3[j*256 + 4*l];
    float acc = 0.f;
    int beg = __builtin_amdgcn_readfirstlane(offs[n]);
    int end = __builtin_amdgcn_readfirstlane(offs[n+1]);
    for (int p = beg; p < end; p++){
        int s = __builtin_amdgcn_readfirstlane(ssnd[p]);
        const float* be = bessp + (size_t)p*8;
        float h1 = 0.f;
        #pragma unroll
        for (int i = 0; i < 8; i++) h1 += be[i] * w1c[i];
        h1 = silu_f(h1);
        float h2 = 0.f;
        #pragma unroll
        for (int j = 0; j < 64; j++) h2 += __shfl(h1, j) * w2c[j];
        h2 = silu_f(h2);
        float rr = 0.f;
        #pragma unroll
        for (int j = 0; j < 64; j++) rr += __shfl(h2, j) * w3c[j];
        acc += h[s*64 + l] * rr;
    }
    A[n*64 + l] = acc * 0.0625f;
}
template<int LAST>
__global__ __launch_bounds__(256) void k_node(const float* __restrict__ A, const float* __restrict__ nf,
        const float* __restrict__ attrs, const float* __restrict__ Wmix0, const float* __restrict__ Wsc,
        const float* __restrict__ Wprod, const float* __restrict__ Wtail, const float* __restrict__ Wml2,
        const float* __restrict__ Wup1, float* __restrict__ nf1out, float* __restrict__ hout,
        void* __restrict__ out, const int* __restrict__ flag){
    int wv = threadIdx.x >> 6;
    int n  = blockIdx.x * 4 + wv;
    int l  = threadIdx.x & 63;
    float Af  = A[n*64 + l];
    float nff = nf[n*64 + l];
    float am = 0.f;
    #pragma unroll 16
    for (int f = 0; f < 64; f++) am += __shfl(Af, f) * Wmix0[f*64 + l];
    float sc = 0.f;
    for (int s = 0; s < 10; s++){
        float av = attrs[n*10 + s];
        if (av != 0.f){
            const float* Ws = Wsc + s*4096;
            float t = 0.f;
            #pragma unroll 16
            for (int f = 0; f < 64; f++) t += __shfl(nff, f) * Ws[f*64 + l];
            sc += av * t;
        }
    }
    float poly = Wprod[l] + Wprod[64 + l]*am + Wprod[128 + l]*am*am;
    float val = am*poly + sc;
    float rv;
    if (LAST == 0){
        nf1out[n*64 + l] = val;
        float hv = 0.f;
        #pragma unroll 16
        for (int g = 0; g < 64; g++) hv += __shfl(val, g) * Wup1[g*64 + l];
        hout[n*64 + l] = hv;
        rv = val * Wtail[l];
    } else {
        int lj = l & 15;
        float t = 0.f;
        #pragma unroll 16
        for (int g = 0; g < 64; g++){
            float vg = __shfl(val, g);
            t += vg * Wtail[g*16 + lj];
        }
        rv = (l < 16) ? (silu_f(t) * Wml2[lj]) : 0.f;
    }
    #pragma unroll
    for (int o2 = 32; o2; o2 >>= 1) rv += __shfl_down(rv, o2);
    if (l == 0){
        int idx = 2*n + LAST;
        if (flag[0] > 100) ((__hip_bfloat16*)out)[idx] = __float2bfloat16(rv);
        else               ((float*)out)[idx] = rv;
    }
}

// ---------------- launch ----------------
extern "C" void kernel_launch(void* const* d_in, const int* in_sizes, int n_in,
                              void* d_out, int out_size, void* d_ws, size_t ws_size,
                              hipStream_t stream) {
    int*   iw = (int*)d_ws;
    float* fw = (float*)d_ws;
    const int* snd = (const int*)d_in[3];
    const int* rcv = (const int*)d_in[4];

    PrepArgs pa;
    const int    pidx[21] = {0,1,2, 5,6,7,8,9,10,11,12,13,14,15,16,17,18,19,20,21,22};
    const size_t pdst[21] = {W_POS, W_ATT, W_SHF,
        W_WGT+OW_EMB, W_WGT+OW_UP0, W_WGT+OW_R10, W_WGT+OW_R20, W_WGT+OW_R30,
        W_WGT+OW_MIX0, W_WGT+OW_SC0, W_WGT+OW_PR0,
        W_WGT+OW_UP1, W_WGT+OW_R11, W_WGT+OW_R21, W_WGT+OW_R31,
        W_WGT+OW_MIX1, W_WGT+OW_SC1, W_WGT+OW_PR1,
        W_WGT+OW_RD0, W_WGT+OW_ML1, W_WGT+OW_ML2};
    const int    pn[21]   = {30000, 100000, 480000,
        640, 4096, 512, 4096, 16384, 16384, 40960, 192,
        4096, 512, 4096, 16384, 16384, 40960, 192, 64, 1024, 16};
    for (int i = 0; i < 21; i++){
        pa.s[i] = d_in[pidx[i]];
        pa.d[i] = fw + pdst[i];
        pa.n[i] = pn[i];
    }

    const int dual   = (ws_size >= NEED_DUAL);
    const int single = (!dual && ws_size >= NEED_SINGLE);
    const size_t wp  = dual ? WP_DUAL : (single ? WP_SINGLE : WP_F);
    const size_t wrs = dual ? W_RS_D  : (single ? W_RS_S  : W_RS_F);

    hipMemsetAsync(iw, 0, (W_CNT + NN) * sizeof(int), stream);   // flag + cnt
    k_dh<<<NE/256, 256, 0, stream>>>((const uint32_t*)d_in[1], rcv, iw + W_FLAG, iw + W_CNT);
    k_scan_prep<<<658, 1024, 0, stream>>>(pa, iw + W_FLAG, iw + W_CNT, iw + W_OFFS, iw + W_CUR,
                                          (u16*)(fw + wp), fw + W_NF0, fw + W_H);
    k_scatter_r<<<NE/256, 256, 0, stream>>>(rcv, snd, d_in[0], d_in[2],
                                            iw + W_CUR, iw + W_SSND, fw + wrs, iw + W_FLAG);

    if (dual){
        k_mlp_mfma<<<1250, 256, 0, stream>>>(fw + wrs, (const u16*)(fw + wp),
                                             (const u16*)(fw + wp) + 10400,
                                             (u16*)(fw + W_R0), (u16*)(fw + W_R1), 625);
        k_gnode<0><<<NN/4, 256, 0, stream>>>(iw+W_OFFS, iw+W_SSND, fw+W_H, (const u16*)(fw+W_R0),
            fw+W_NF0, fw+W_ATT, fw+W_WGT+OW_MIX0, fw+W_WGT+OW_SC0, fw+W_WGT+OW_PR0,
            fw+W_WGT+OW_RD0, nullptr, fw+W_WGT+OW_UP1, fw+W_NF1, fw+W_A, d_out, iw+W_FLAG);
        k_gnode<1><<<NN/4, 256, 0, stream>>>(iw+W_OFFS, iw+W_SSND, fw+W_A, (const u16*)(fw+W_R1),
            fw+W_NF1, fw+W_ATT, fw+W_WGT+OW_MIX1, fw+W_WGT+OW_SC1, fw+W_WGT+OW_PR1,
            fw+W_WGT+OW_ML1, fw+W_WGT+OW_ML2, nullptr, nullptr, nullptr, d_out, iw+W_FLAG);
    } else if (single){
        k_mlp_mfma<<<625, 256, 0, stream>>>(fw + wrs, (const u16*)(fw + wp),
                                            (const u16*)(fw + wp),
                                            (u16*)(fw + W_R0), (u16*)(fw + W_R0), 2000000);
        k_gnode<0><<<NN/4, 256, 0, stream>>>(iw+W_OFFS, iw+W_SSND, fw+W_H, (const u16*)(fw+W_R0),
            fw+W_NF0, fw+W_ATT, fw+W_WGT+OW_MIX0, fw+W_WGT+OW_SC0, fw+W_WGT+OW_PR0,
            fw+W_WGT+OW_RD0, nullptr, fw+W_WGT+OW_UP1, fw+W_NF1, fw+W_A, d_out, iw+W_FLAG);
        k_mlp_mfma<<<625, 256, 0, stream>>>(fw + wrs, (const u16*)(fw + wp) + 10400,
                                            (const u16*)(fw + wp) + 10400,
                                            (u16*)(fw + W_R0), (u16*)(fw + W_R0), 2000000);
        k_gnode<1><<<NN/4, 256, 0, stream>>>(iw+W_OFFS, iw+W_SSND, fw+W_A, (const u16*)(fw+W_R0),
            fw+W_NF1, fw+W_ATT, fw+W_WGT+OW_MIX1, fw+W_WGT+OW_SC1, fw+W_WGT+OW_PR1,
            fw+W_WGT+OW_ML1, fw+W_WGT+OW_ML2, nullptr, nullptr, nullptr, d_out, iw+W_FLAG);
    } else {
        // fallback tier: bessel buffer + VALU msg kernels (rs lives at W_R0 slot)
        k_bess<<<NE/256, 256, 0, stream>>>(fw + wrs, fw + W_BES);
        k_msg_fused<<<NN/4, 256, 0, stream>>>(iw+W_OFFS, iw+W_SSND, fw+W_H, fw+W_BES,
                                              fw+W_WGT+OW_R10, fw+W_WGT+OW_R20,
                                              fw+W_WGT+OW_R30, fw + W_A);
        k_node<0><<<NN/4, 256, 0, stream>>>(fw + W_A, fw + W_NF0, fw + W_ATT,
                                            fw + W_WGT + OW_MIX0, fw + W_WGT + OW_SC0,
                                            fw + W_WGT + OW_PR0, fw + W_WGT + OW_RD0, nullptr,
                                            fw + W_WGT + OW_UP1, fw + W_NF1, fw + W_H,
                                            d_out, iw + W_FLAG);
        k_msg_fused<<<NN/4, 256, 0, stream>>>(iw+W_OFFS, iw+W_SSND, fw+W_H, fw+W_BES,
                                              fw+W_WGT+OW_R11, fw+W_WGT+OW_R21,
                                              fw+W_WGT+OW_R31, fw + W_A);
        k_node<1><<<NN/4, 256, 0, stream>>>(fw + W_A, fw + W_NF1, fw + W_ATT,
                                            fw + W_WGT + OW_MIX1, fw + W_WGT + OW_SC1,
                                            fw + W_WGT + OW_PR1, fw + W_WGT + OW_ML1,
                                            fw + W_WGT + OW_ML2, nullptr, nullptr, nullptr,
                                            d_out, iw + W_FLAG);
    }
}

// Round 2
// 224.228 us; speedup vs baseline: 1.0210x; 1.0210x over previous
//
#include <hip/hip_runtime.h>
#include <hip/hip_bf16.h>
#include <cstdint>
#include <cstddef>

#define NN 10000
#define NE 160000

typedef unsigned short u16;
typedef __attribute__((ext_vector_type(8))) short short8;
typedef __attribute__((ext_vector_type(4))) float f32x4;

__device__ __forceinline__ float b2f(u16 u){
    union { uint32_t i; float f; } v; v.i = ((uint32_t)u) << 16; return v.f;
}
__device__ __forceinline__ u16 f2b(float f){
    union { __hip_bfloat16 h; u16 u; } c; c.h = __float2bfloat16(f); return c.u;
}
__device__ __forceinline__ float silu_f(float x){ return x / (1.f + __expf(-x)); }
__device__ __forceinline__ float ldr(const void* p, int i, int bf){
    return bf ? b2f(((const u16*)p)[i]) : ((const float*)p)[i];
}

// ---------------- workspace layout (4-byte word offsets) ----------------
constexpr size_t W_FLAG = 0;                        // 16 (flag[0] = anomaly count)
constexpr size_t W_CNT  = 16;                       // 10000
constexpr size_t W_OFFS = 10016;                    // 10001
constexpr size_t W_CUR  = 20032;                    // 10000
constexpr size_t W_SSND = 30032;                    // 160000 (sender per sorted pos)
constexpr size_t W_ATT  = 350032;                   // 100000
constexpr size_t W_POS  = 450032;                   // 30000
constexpr size_t W_SHF  = 480032;                   // 480000
constexpr size_t W_WGT  = 960032;
constexpr size_t OW_EMB = 0;
constexpr size_t OW_UP0 = 640;
constexpr size_t OW_R10 = 4736;
constexpr size_t OW_R20 = 5248;
constexpr size_t OW_R30 = 9344;
constexpr size_t OW_MIX0= 25728;
constexpr size_t OW_SC0 = 42112;
constexpr size_t OW_PR0 = 83072;
constexpr size_t OW_UP1 = 83264;
constexpr size_t OW_R11 = 87360;
constexpr size_t OW_R21 = 87872;
constexpr size_t OW_R31 = 91968;
constexpr size_t OW_MIX1= 108352;
constexpr size_t OW_SC1 = 124736;
constexpr size_t OW_PR1 = 165696;
constexpr size_t OW_RD0 = 165888;
constexpr size_t OW_ML1 = 165952;
constexpr size_t OW_ML2 = 166976;
constexpr size_t OW_TEND = 167000;
constexpr size_t W_BES  = W_WGT + OW_TEND;          // [E][8] f32 (fallback tier only)
constexpr size_t W_NF0  = W_BES + (size_t)NE*8;     // [N,64]
constexpr size_t W_H    = W_NF0 + (size_t)NN*64;
constexpr size_t W_A    = W_H   + (size_t)NN*64;    // h1 buffer in fused path; A in fallback
constexpr size_t W_NF1  = W_A   + (size_t)NN*64;
constexpr size_t W_R0   = W_NF1 + (size_t)NN*64;    // [E][64] bf16, RECEIVER-SORTED
constexpr size_t W_R1   = W_R0  + (size_t)NE*32;
constexpr size_t WP_DUAL   = W_R1 + (size_t)NE*32;  // packed weights 2 x 10400 u16
constexpr size_t WP_SINGLE = W_R0 + (size_t)NE*32;
constexpr size_t W_RS_D = WP_DUAL   + 10400;        // sorted distances [E] f32
constexpr size_t W_RS_S = WP_SINGLE + 10400;
constexpr size_t W_RS_F = W_R0;                     // fallback: rs at R0 slot (no R in fallback)
constexpr size_t WP_F   = W_R0 + NE;                // fallback: dummy wpack target

constexpr size_t NEED_DUAL   = (W_RS_D + NE) * 4;   // ~61.5 MB (ws measured ~268 MB)
constexpr size_t NEED_SINGLE = (W_RS_S + NE) * 4;   // ~41.0 MB

constexpr int OCT  = 520;   // weight per-oct stride (u16)
constexpr int OCTS = 136;   // activation per-oct stride (u16), 16 rows

// ---------------- detect (dtype) + histogram, one grid ----------------
__global__ void k_dh(const uint32_t* __restrict__ attrs, const int* __restrict__ rcv,
                     int* __restrict__ flag, int* __restrict__ cnt){
    int i = blockIdx.x * 256 + threadIdx.x;          // 625*256 == NE
    int c = 0;
    if (i < 50000){
        uint32_t v = attrs[i];
        c = (v != 0u && v != 0x3F800000u) ? 1 : 0;
    }
    unsigned long long m = __ballot(c);
    if ((threadIdx.x & 63) == 0 && m)
        atomicAdd(flag, (int)__popcll(m));
    if (i < NE) atomicAdd(&cnt[rcv[i]], 1);
}

// ---------------- merged: scan (block 0) + convert (1..64) + wpack (65..66) + embed_h (67..691) ----------------
struct PrepArgs { const void* s[21]; float* d[21]; int n[21]; };
__global__ __launch_bounds__(1024) void k_scan_prep(PrepArgs a, const int* __restrict__ flag,
        const int* __restrict__ cnt, int* __restrict__ offs, int* __restrict__ cur,
        u16* __restrict__ WP, float* __restrict__ nf0, float* __restrict__ h){
    int bf = flag[0] > 100;
    int t = threadIdx.x;
    if (blockIdx.x == 0){
        __shared__ int cl[10000];
        __shared__ int part[1024];
        for (int i = t; i < 10000; i += 1024) cl[i] = cnt[i];
        __syncthreads();
        int base = t * 10;
        int s = 0;
        #pragma unroll
        for (int i = 0; i < 10; i++) if (base + i < NN) s += cl[base + i];
        part[t] = s; __syncthreads();
        for (int d = 1; d < 1024; d <<= 1){
            int v = part[t];
            if (t >= d) v += part[t - d];
            __syncthreads();
            part[t] = v;
            __syncthreads();
        }
        int run = part[t] - s;
        #pragma unroll
        for (int i = 0; i < 10; i++){
            int idx = base + i;
            if (idx < NN){ offs[idx] = run; cur[idx] = run; run += cl[idx]; }
        }
        if (t == 1023) offs[NN] = part[1023];
    } else if (blockIdx.x < 65){
        // vectorized convert: all n are %4==0, all dst word-offsets %4==0
        int stride = 64 * 1024;
        int t0 = (blockIdx.x - 1) * 1024 + t;
        for (int k = 0; k < 21; k++){
            float* d = a.d[k]; int n4 = a.n[k] >> 2;
            if (bf){
                const uint2* s = (const uint2*)a.s[k];
                for (int i = t0; i < n4; i += stride){
                    uint2 v = s[i];
                    float4 o;
                    o.x = b2f((u16)(v.x & 0xffffu));
                    o.y = b2f((u16)(v.x >> 16));
                    o.z = b2f((u16)(v.y & 0xffffu));
                    o.w = b2f((u16)(v.y >> 16));
                    ((float4*)d)[i] = o;
                }
            } else {
                const float4* s = (const float4*)a.s[k];
                for (int i = t0; i < n4; i += stride) ((float4*)d)[i] = s[i];
            }
        }
    } else if (blockIdx.x < 67){
        int b = blockIdx.x - 65;
        const void* W1 = a.s[b ? 12 : 5];
        const void* W2 = a.s[b ? 13 : 6];
        const void* W3 = a.s[b ? 14 : 7];
        u16* dst = WP + b * 10400;
        for (int i = t; i < 5200; i += 1024) ((uint32_t*)dst)[i] = 0;
        __syncthreads();
        for (int i = t; i < 512; i += 1024){
            int n = i >> 3, k = i & 7;
            dst[n*8 + k] = f2b(ldr(W1, k*64 + n, bf));
        }
        for (int i = t; i < 2048; i += 1024){
            int k = (i >> 6) * 2, n = i & 63;
            uint32_t p2 = ((uint32_t)f2b(ldr(W2, (k+1)*64 + n, bf)) << 16) | f2b(ldr(W2, k*64 + n, bf));
            uint32_t p3 = ((uint32_t)f2b(ldr(W3, (k+1)*256 + 4*n, bf)) << 16) | f2b(ldr(W3, k*256 + 4*n, bf));
            *(uint32_t*)&dst[2080 + (k>>3)*OCT + n*8 + (k&7)] = p2;
            *(uint32_t*)&dst[6240 + (k>>3)*OCT + n*8 + (k&7)] = p3;
        }
    } else {
        int nb = blockIdx.x - 67;                  // [0, 625): 16 nodes per block
        int n = nb*16 + (t >> 6);
        int l = t & 63;
        const void* attrs = a.s[1];
        const void* Wemb  = a.s[3];
        const void* Wup0  = a.s[4];
        float acc = 0.f;
        #pragma unroll
        for (int s = 0; s < 10; s++) acc += ldr(attrs, n*10 + s, bf) * ldr(Wemb, s*64 + l, bf);
        nf0[n*64 + l] = acc;
        float hv = 0.f;
        #pragma unroll 16
        for (int g = 0; g < 64; g++) hv += __shfl(acc, g) * ldr(Wup0, g*64 + l, bf);
        h[n*64 + l] = hv;
    }
}

// ---------------- scatter edge -> sorted slot; fused distance (raw inputs) ----------------
__global__ void k_scatter_r(const int* __restrict__ rcv, const int* __restrict__ snd,
        const void* __restrict__ posr, const void* __restrict__ shfr,
        int* __restrict__ cur, int* __restrict__ ssnd, float* __restrict__ rs,
        const int* __restrict__ flag){
    int e = blockIdx.x * 256 + threadIdx.x;
    if (e >= NE) return;
    int bf = flag[0] > 100;
    int r = rcv[e], s = snd[e];
    float vx = ldr(posr, r*3+0, bf) - ldr(posr, s*3+0, bf) + ldr(shfr, e*3+0, bf);
    float vy = ldr(posr, r*3+1, bf) - ldr(posr, s*3+1, bf) + ldr(shfr, e*3+1, bf);
    float vz = ldr(posr, r*3+2, bf) - ldr(posr, s*3+2, bf) + ldr(shfr, e*3+2, bf);
    float rr = sqrtf(vx*vx + vy*vy + vz*vz);
    int p = atomicAdd(&cur[r], 1);
    ssnd[p] = s;
    rs[p] = rr;
}

// ---------------- bessel expansion (fallback tier only) ----------------
__global__ void k_bess(const float* __restrict__ rs, float* __restrict__ bessp){
    int p = blockIdx.x * 256 + threadIdx.x;
    if (p >= NE) return;
    float rr = rs[p];
    float xr = rr * 0.1f;
    float x2 = xr*xr; float x5 = x2*x2*xr;
    float env = 1.f - 21.f*x5 + 35.f*x5*xr - 15.f*x5*x2;
    if (xr >= 1.f) env = 0.f;
    float scl = 0.4472135954999579f * env / (rr + 1e-9f);
    float b[8];
    #pragma unroll
    for (int n = 1; n <= 8; n++)
        b[n-1] = scl * sinf((float)n * 3.14159265358979323846f * rr * 0.1f);
    float4* be = (float4*)(bessp + (size_t)p*8);
    be[0] = make_float4(b[0], b[1], b[2], b[3]);
    be[1] = make_float4(b[4], b[5], b[6], b[7]);
}

// ---------------- MFMA radial MLP: block = 256 edges; bessel computed inline from rs ----------------
// Grid must be 2*nblk0 (dual) or nblk0 >= gridDim.x (single); nblk0 = NE/256 = 625 per half.
__global__ __launch_bounds__(256) void k_mlp_mfma(const float* __restrict__ rs,
        const u16* __restrict__ WPa, const u16* __restrict__ WPb,
        u16* __restrict__ R0, u16* __restrict__ R1, int nblk0){
    __shared__ __align__(16) u16 W[10400];
    __shared__ __align__(16) u16 X[4][20*OCTS];
    int half = blockIdx.x >= nblk0;
    int blk  = half ? blockIdx.x - nblk0 : blockIdx.x;
    const u16* WP = half ? WPb : WPa;
    u16* R = half ? R1 : R0;
    int t = threadIdx.x;
    int w = t >> 6, lane = t & 63;
    int q = lane >> 4, r = lane & 15;
    u16* Xw = &X[w][0];
    // stage pre-packed weights: 10400 u16 = 1300 uint4
    for (int i = t; i < 1300; i += 256) ((uint4*)W)[i] = ((const uint4*)WP)[i];
    // zero Xc octs 1..3 (K-padding), per-wave region
    {
        uint32_t* xz = (uint32_t*)(Xw + OCTS);
        for (int i = lane; i < 204; i += 64) xz[i] = 0;
    }
    __syncthreads();
    int pbase = blk * 256 + w * 64;
    #pragma unroll 1
    for (int st = 0; st < 4; st++){
        int pb = pbase + st * 16;
        // bessel inline: lane covers (edge = lane>>2, k = 2*(lane&3), +1)
        {
            float rr = rs[pb + (lane >> 2)];
            float xr = rr * 0.1f;
            float x2 = xr*xr, x5 = x2*x2*xr;
            float env = 1.f - 21.f*x5 + 35.f*x5*xr - 15.f*x5*x2;
            if (xr >= 1.f) env = 0.f;
            float scl = 0.4472135954999579f * env / (rr + 1e-9f);
            int k0 = (lane & 3) * 2;
            float b0 = scl * __sinf((float)(k0+1) * 0.3141592653589793f * rr);
            float b1 = scl * __sinf((float)(k0+2) * 0.3141592653589793f * rr);
            ((uint32_t*)Xw)[lane] = ((uint32_t)f2b(b1) << 16) | f2b(b0);
        }
        // ---- layer 1: K=8 (padded to 32) ----
        {
            short8 a = *(const short8*)&Xw[q*OCTS + r*8];
            #pragma unroll
            for (int nt = 0; nt < 4; nt++){
                short8 b = *(const short8*)&W[q*OCT + (nt*16 + r)*8];
                f32x4 c = {0.f, 0.f, 0.f, 0.f};
                c = __builtin_amdgcn_mfma_f32_16x16x32_bf16(a, b, c, 0, 0, 0);
                #pragma unroll
                for (int g = 0; g < 4; g++){
                    int e = q*4 + g;
                    int n = nt*16 + r;
                    Xw[(4 + (n>>3))*OCTS + e*8 + (n&7)] = f2b(silu_f(c[g]));
                }
            }
        }
        // ---- layer 2: K=64 ----
        {
            short8 a0 = *(const short8*)&Xw[(4+q)*OCTS + r*8];
            short8 a1 = *(const short8*)&Xw[(8+q)*OCTS + r*8];
            #pragma unroll
            for (int nt = 0; nt < 4; nt++){
                short8 b0 = *(const short8*)&W[2080 + q*OCT + (nt*16 + r)*8];
                short8 b1 = *(const short8*)&W[2080 + (4+q)*OCT + (nt*16 + r)*8];
                f32x4 c = {0.f, 0.f, 0.f, 0.f};
                c = __builtin_amdgcn_mfma_f32_16x16x32_bf16(a0, b0, c, 0, 0, 0);
                c = __builtin_amdgcn_mfma_f32_16x16x32_bf16(a1, b1, c, 0, 0, 0);
                #pragma unroll
                for (int g = 0; g < 4; g++){
                    int e = q*4 + g;
                    int n = nt*16 + r;
                    Xw[(12 + (n>>3))*OCTS + e*8 + (n&7)] = f2b(silu_f(c[g]));
                }
            }
        }
        // ---- layer 3: K=64, store R (bf16, receiver-sorted) ----
        {
            short8 a0 = *(const short8*)&Xw[(12+q)*OCTS + r*8];
            short8 a1 = *(const short8*)&Xw[(16+q)*OCTS + r*8];
            #pragma unroll
            for (int nt = 0; nt < 4; nt++){
                short8 b0 = *(const short8*)&W[6240 + q*OCT + (nt*16 + r)*8];
                short8 b1 = *(const short8*)&W[6240 + (4+q)*OCT + (nt*16 + r)*8];
                f32x4 c = {0.f, 0.f, 0.f, 0.f};
                c = __builtin_amdgcn_mfma_f32_16x16x32_bf16(a0, b0, c, 0, 0, 0);
                c = __builtin_amdgcn_mfma_f32_16x16x32_bf16(a1, b1, c, 0, 0, 0);
                #pragma unroll
                for (int g = 0; g < 4; g++){
                    int e = q*4 + g;
                    int n = nt*16 + r;
                    R[(size_t)(pb + e)*64 + n] = f2b(c[g]);
                }
            }
        }
    }
}

// ---------------- fused gather + node update + readout ----------------
template<int LAST>
__global__ __launch_bounds__(256) void k_gnode(const int* __restrict__ offs,
        const int* __restrict__ ssnd, const float* __restrict__ h, const u16* __restrict__ R,
        const float* __restrict__ nf, const float* __restrict__ attrs,
        const float* __restrict__ Wmix0, const float* __restrict__ Wsc,
        const float* __restrict__ Wprod, const float* __restrict__ Wtail,
        const float* __restrict__ Wml2, const float* __restrict__ Wup1,
        float* __restrict__ nf1out, float* __restrict__ hout,
        void* __restrict__ out, const int* __restrict__ flag){
    int wv = threadIdx.x >> 6;
    int n  = blockIdx.x * 4 + wv;
    int l  = threadIdx.x & 63;
    int beg = __builtin_amdgcn_readfirstlane(offs[n]);
    int end = __builtin_amdgcn_readfirstlane(offs[n+1]);
    float acc = 0.f;
    // register-cached senders: one coalesced wave-load per 64-edge segment,
    // then v_readlane (no memory latency on the sender index path).
    for (int c = beg; c < end; c += 64){
        int ld = c + l; if (ld >= end) ld = end - 1;
        int sv = ssnd[ld];
        int m = end - c; if (m > 64) m = 64;
        int j = 0;
        for (; j + 4 <= m; j += 4){
            int s0 = __builtin_amdgcn_readlane(sv, j+0);
            int s1 = __builtin_amdgcn_readlane(sv, j+1);
            int s2 = __builtin_amdgcn_readlane(sv, j+2);
            int s3 = __builtin_amdgcn_readlane(sv, j+3);
            float r0 = b2f(R[(size_t)(c+j+0)*64 + l]);
            float r1 = b2f(R[(size_t)(c+j+1)*64 + l]);
            float r2 = b2f(R[(size_t)(c+j+2)*64 + l]);
            float r3 = b2f(R[(size_t)(c+j+3)*64 + l]);
            acc += h[s0*64 + l]*r0 + h[s1*64 + l]*r1 + h[s2*64 + l]*r2 + h[s3*64 + l]*r3;
        }
        for (; j < m; j++){
            int s = __builtin_amdgcn_readlane(sv, j);
            acc += h[s*64 + l] * b2f(R[(size_t)(c+j)*64 + l]);
        }
    }
    float Af  = acc * 0.0625f;
    float nff = nf[n*64 + l];
    float am = 0.f;
    #pragma unroll 16
    for (int f = 0; f < 64; f++) am += __shfl(Af, f) * Wmix0[f*64 + l];
    float sc = 0.f;
    for (int s = 0; s < 10; s++){
        float av = attrs[n*10 + s];       // wave-uniform
        if (av != 0.f){
            const float* Ws = Wsc + s*4096;
            float t = 0.f;
            #pragma unroll 16
            for (int f = 0; f < 64; f++) t += __shfl(nff, f) * Ws[f*64 + l];
            sc += av * t;
        }
    }
    float poly = Wprod[l] + Wprod[64 + l]*am + Wprod[128 + l]*am*am;
    float val = am*poly + sc;
    float rv;
    if (LAST == 0){
        nf1out[n*64 + l] = val;
        float hv = 0.f;
        #pragma unroll 16
        for (int g = 0; g < 64; g++) hv += __shfl(val, g) * Wup1[g*64 + l];
        hout[n*64 + l] = hv;              // separate buffer: h is still being gathered by other blocks
        rv = val * Wtail[l];
    } else {
        int lj = l & 15;                  // all 64 lanes run the shfl loop (divergent shfl is UB)
        float t = 0.f;
        #pragma unroll 16
        for (int g = 0; g < 64; g++){
            float vg = __shfl(val, g);
            t += vg * Wtail[g*16 + lj];
        }
        rv = (l < 16) ? (silu_f(t) * Wml2[lj]) : 0.f;
    }
    #pragma unroll
    for (int o2 = 32; o2; o2 >>= 1) rv += __shfl_down(rv, o2);
    if (l == 0){
        int idx = 2*n + LAST;
        if (flag[0] > 100) ((__hip_bfloat16*)out)[idx] = __float2bfloat16(rv);
        else               ((float*)out)[idx] = rv;
    }
}

// ---------------- legacy fused msg + node (fallback tier only) ----------------
__global__ __launch_bounds__(256) void k_msg_fused(const int* __restrict__ offs,
        const int* __restrict__ ssnd, const float* __restrict__ h, const float* __restrict__ bessp,
        const float* __restrict__ W1, const float* __restrict__ W2, const float* __restrict__ W3,
        float* __restrict__ A){
    int wv = threadIdx.x >> 6;
    int n  = blockIdx.x * 4 + wv;
    int l  = threadIdx.x & 63;
    float w1c[8];
    #pragma unroll
    for (int i = 0; i < 8; i++) w1c[i] = W1[i*64 + l];
    float w2c[64];
    #pragma unroll
    for (int j = 0; j < 64; j++) w2c[j] = W2[j*64 + l];
    float w3c[64];
    #pragma unroll
    for (int j = 0; j < 64; j++) w3c[j] = W3[j*256 + 4*l];
    float acc = 0.f;
    int beg = __builtin_amdgcn_readfirstlane(offs[n]);
    int end = __builtin_amdgcn_readfirstlane(offs[n+1]);
    for (int p = beg; p < end; p++){
        int s = __builtin_amdgcn_readfirstlane(ssnd[p]);
        const float* be = bessp + (size_t)p*8;
        float h1 = 0.f;
        #pragma unroll
        for (int i = 0; i < 8; i++) h1 += be[i] * w1c[i];
        h1 = silu_f(h1);
        float h2 = 0.f;
        #pragma unroll
        for (int j = 0; j < 64; j++) h2 += __shfl(h1, j) * w2c[j];
        h2 = silu_f(h2);
        float rr = 0.f;
        #pragma unroll
        for (int j = 0; j < 64; j++) rr += __shfl(h2, j) * w3c[j];
        acc += h[s*64 + l] * rr;
    }
    A[n*64 + l] = acc * 0.0625f;
}
template<int LAST>
__global__ __launch_bounds__(256) void k_node(const float* __restrict__ A, const float* __restrict__ nf,
        const float* __restrict__ attrs, const float* __restrict__ Wmix0, const float* __restrict__ Wsc,
        const float* __restrict__ Wprod, const float* __restrict__ Wtail, const float* __restrict__ Wml2,
        const float* __restrict__ Wup1, float* __restrict__ nf1out, float* __restrict__ hout,
        void* __restrict__ out, const int* __restrict__ flag){
    int wv = threadIdx.x >> 6;
    int n  = blockIdx.x * 4 + wv;
    int l  = threadIdx.x & 63;
    float Af  = A[n*64 + l];
    float nff = nf[n*64 + l];
    float am = 0.f;
    #pragma unroll 16
    for (int f = 0; f < 64; f++) am += __shfl(Af, f) * Wmix0[f*64 + l];
    float sc = 0.f;
    for (int s = 0; s < 10; s++){
        float av = attrs[n*10 + s];
        if (av != 0.f){
            const float* Ws = Wsc + s*4096;
            float t = 0.f;
            #pragma unroll 16
            for (int f = 0; f < 64; f++) t += __shfl(nff, f) * Ws[f*64 + l];
            sc += av * t;
        }
    }
    float poly = Wprod[l] + Wprod[64 + l]*am + Wprod[128 + l]*am*am;
    float val = am*poly + sc;
    float rv;
    if (LAST == 0){
        nf1out[n*64 + l] = val;
        float hv = 0.f;
        #pragma unroll 16
        for (int g = 0; g < 64; g++) hv += __shfl(val, g) * Wup1[g*64 + l];
        hout[n*64 + l] = hv;
        rv = val * Wtail[l];
    } else {
        int lj = l & 15;
        float t = 0.f;
        #pragma unroll 16
        for (int g = 0; g < 64; g++){
            float vg = __shfl(val, g);
            t += vg * Wtail[g*16 + lj];
        }
        rv = (l < 16) ? (silu_f(t) * Wml2[lj]) : 0.f;
    }
    #pragma unroll
    for (int o2 = 32; o2; o2 >>= 1) rv += __shfl_down(rv, o2);
    if (l == 0){
        int idx = 2*n + LAST;
        if (flag[0] > 100) ((__hip_bfloat16*)out)[idx] = __float2bfloat16(rv);
        else               ((float*)out)[idx] = rv;
    }
}

// ---------------- launch ----------------
extern "C" void kernel_launch(void* const* d_in, const int* in_sizes, int n_in,
                              void* d_out, int out_size, void* d_ws, size_t ws_size,
                              hipStream_t stream) {
    int*   iw = (int*)d_ws;
    float* fw = (float*)d_ws;
    const int* snd = (const int*)d_in[3];
    const int* rcv = (const int*)d_in[4];

    PrepArgs pa;
    const int    pidx[21] = {0,1,2, 5,6,7,8,9,10,11,12,13,14,15,16,17,18,19,20,21,22};
    const size_t pdst[21] = {W_POS, W_ATT, W_SHF,
        W_WGT+OW_EMB, W_WGT+OW_UP0, W_WGT+OW_R10, W_WGT+OW_R20, W_WGT+OW_R30,
        W_WGT+OW_MIX0, W_WGT+OW_SC0, W_WGT+OW_PR0,
        W_WGT+OW_UP1, W_WGT+OW_R11, W_WGT+OW_R21, W_WGT+OW_R31,
        W_WGT+OW_MIX1, W_WGT+OW_SC1, W_WGT+OW_PR1,
        W_WGT+OW_RD0, W_WGT+OW_ML1, W_WGT+OW_ML2};
    const int    pn[21]   = {30000, 100000, 480000,
        640, 4096, 512, 4096, 16384, 16384, 40960, 192,
        4096, 512, 4096, 16384, 16384, 40960, 192, 64, 1024, 16};
    for (int i = 0; i < 21; i++){
        pa.s[i] = d_in[pidx[i]];
        pa.d[i] = fw + pdst[i];
        pa.n[i] = pn[i];
    }

    const int dual   = (ws_size >= NEED_DUAL);
    const int single = (!dual && ws_size >= NEED_SINGLE);
    const size_t wp  = dual ? WP_DUAL : (single ? WP_SINGLE : WP_F);
    const size_t wrs = dual ? W_RS_D  : (single ? W_RS_S  : W_RS_F);

    hipMemsetAsync(iw, 0, (W_CNT + NN) * sizeof(int), stream);   // flag + cnt
    k_dh<<<NE/256, 256, 0, stream>>>((const uint32_t*)d_in[1], rcv, iw + W_FLAG, iw + W_CNT);
    k_scan_prep<<<692, 1024, 0, stream>>>(pa, iw + W_FLAG, iw + W_CNT, iw + W_OFFS, iw + W_CUR,
                                          (u16*)(fw + wp), fw + W_NF0, fw + W_H);
    k_scatter_r<<<NE/256, 256, 0, stream>>>(rcv, snd, d_in[0], d_in[2],
                                            iw + W_CUR, iw + W_SSND, fw + wrs, iw + W_FLAG);

    if (dual){
        k_mlp_mfma<<<1250, 256, 0, stream>>>(fw + wrs, (const u16*)(fw + wp),
                                             (const u16*)(fw + wp) + 10400,
                                             (u16*)(fw + W_R0), (u16*)(fw + W_R1), 625);
        k_gnode<0><<<NN/4, 256, 0, stream>>>(iw+W_OFFS, iw+W_SSND, fw+W_H, (const u16*)(fw+W_R0),
            fw+W_NF0, fw+W_ATT, fw+W_WGT+OW_MIX0, fw+W_WGT+OW_SC0, fw+W_WGT+OW_PR0,
            fw+W_WGT+OW_RD0, nullptr, fw+W_WGT+OW_UP1, fw+W_NF1, fw+W_A, d_out, iw+W_FLAG);
        k_gnode<1><<<NN/4, 256, 0, stream>>>(iw+W_OFFS, iw+W_SSND, fw+W_A, (const u16*)(fw+W_R1),
            fw+W_NF1, fw+W_ATT, fw+W_WGT+OW_MIX1, fw+W_WGT+OW_SC1, fw+W_WGT+OW_PR1,
            fw+W_WGT+OW_ML1, fw+W_WGT+OW_ML2, nullptr, nullptr, nullptr, d_out, iw+W_FLAG);
    } else if (single){
        k_mlp_mfma<<<625, 256, 0, stream>>>(fw + wrs, (const u16*)(fw + wp),
                                            (const u16*)(fw + wp),
                                            (u16*)(fw + W_R0), (u16*)(fw + W_R0), 2000000);
        k_gnode<0><<<NN/4, 256, 0, stream>>>(iw+W_OFFS, iw+W_SSND, fw+W_H, (const u16*)(fw+W_R0),
            fw+W_NF0, fw+W_ATT, fw+W_WGT+OW_MIX0, fw+W_WGT+OW_SC0, fw+W_WGT+OW_PR0,
            fw+W_WGT+OW_RD0, nullptr, fw+W_WGT+OW_UP1, fw+W_NF1, fw+W_A, d_out, iw+W_FLAG);
        k_mlp_mfma<<<625, 256, 0, stream>>>(fw + wrs, (const u16*)(fw + wp) + 10400,
                                            (const u16*)(fw + wp) + 10400,
                                            (u16*)(fw + W_R0), (u16*)(fw + W_R0), 2000000);
        k_gnode<1><<<NN/4, 256, 0, stream>>>(iw+W_OFFS, iw+W_SSND, fw+W_A, (const u16*)(fw+W_R0),
            fw+W_NF1, fw+W_ATT, fw+W_WGT+OW_MIX1, fw+W_WGT+OW_SC1, fw+W_WGT+OW_PR1,
            fw+W_WGT+OW_ML1, fw+W_WGT+OW_ML2, nullptr, nullptr, nullptr, d_out, iw+W_FLAG);
    } else {
        // fallback tier: bessel buffer + VALU msg kernels (rs lives at W_R0 slot)
        k_bess<<<NE/256, 256, 0, stream>>>(fw + wrs, fw + W_BES);
        k_msg_fused<<<NN/4, 256, 0, stream>>>(iw+W_OFFS, iw+W_SSND, fw+W_H, fw+W_BES,
                                              fw+W_WGT+OW_R10, fw+W_WGT+OW_R20,
                                              fw+W_WGT+OW_R30, fw + W_A);
        k_node<0><<<NN/4, 256, 0, stream>>>(fw + W_A, fw + W_NF0, fw + W_ATT,
                                            fw + W_WGT + OW_MIX0, fw + W_WGT + OW_SC0,
                                            fw + W_WGT + OW_PR0, fw + W_WGT + OW_RD0, nullptr,
                                            fw + W_WGT + OW_UP1, fw + W_NF1, fw + W_H,
                                            d_out, iw + W_FLAG);
        k_msg_fused<<<NN/4, 256, 0, stream>>>(iw+W_OFFS, iw+W_SSND, fw+W_H, fw+W_BES,
                                              fw+W_WGT+OW_R11, fw+W_WGT+OW_R21,
                                              fw+W_WGT+OW_R31, fw + W_A);
        k_node<1><<<NN/4, 256, 0, stream>>>(fw + W_A, fw + W_NF1, fw + W_ATT,
                                            fw + W_WGT + OW_MIX1, fw + W_WGT + OW_SC1,
                                            fw + W_WGT + OW_PR1, fw + W_WGT + OW_ML1,
                                            fw + W_WGT + OW_ML2, nullptr, nullptr, nullptr,
                                            d_out, iw + W_FLAG);
    }
}